// Round 18
// baseline (100.325 us; speedup 1.0000x reference)
//
#include <hip/hip_runtime.h>
#include <hip/hip_bf16.h>

// SDPA, causal, b=16 t=2048 d=64. Outputs FP32: d_out = [ out | sm_qk ].
// R18 = R17 + zero-fill interleaved into phase 1 (retry of R11's idea, now
// valid: in-loop barriers are lgkm-only since R12, so the zero stores stay
// in flight across BAR() instead of being drained into each round's chain).
// Block qb: zcnt=31-qb masked tiles spread over nkt1 phase-1 rounds
// (zpr=ceil(zcnt/nkt1) per round); end-of-kernel zero-fill tail removed.
// R17 base: 8-wave blocks; phase-1 KT1=128 via LDS overlay; phase-2 T15
// pipeline (PV(kt-1)||QKT(kt)), role-split staging, Q-side-compensated
// QK^T, P=exp*il direct-stored; pairing (c,31-c).

#define BATCHES 16
#define SEQ 2048
#define DIM 64
#define QB 64
#define KT 64
#define KT1 128
#define NQB (SEQ / QB) /* 32 */
#define KLD 72
#define VLD 72
#define PBLD 72

#define BAR() do { asm volatile("s_waitcnt lgkmcnt(0)" ::: "memory"); \
                   __builtin_amdgcn_s_barrier(); } while (0)

typedef __attribute__((ext_vector_type(8))) short bf16x8;
typedef __attribute__((ext_vector_type(4))) short short4v;
typedef __attribute__((ext_vector_type(4))) float f32x4;

static __device__ __forceinline__ short f2bf(float f) {
    return __builtin_bit_cast(short, __float2bfloat16(f));
}
static __device__ __forceinline__ float bf2f(short s) {
    unsigned int u = ((unsigned int)(unsigned short)s) << 16;
    return __builtin_bit_cast(float, u);
}
static __device__ __forceinline__ void split8(f32x4 a, f32x4 b, float sc,
                                              bf16x8& hh, bf16x8& ll) {
#pragma unroll
    for (int e = 0; e < 4; ++e) {
        float x = a[e] * sc; short hb = f2bf(x);
        hh[e] = hb; ll[e] = f2bf(x - bf2f(hb));
    }
#pragma unroll
    for (int e = 0; e < 4; ++e) {
        float x = b[e] * sc; short hb = f2bf(x);
        hh[4 + e] = hb; ll[4 + e] = f2bf(x - bf2f(hb));
    }
}

// LDS budget (bytes): phase2 Khi 18432 | Vt 27648 | Pb 18432 | lS 512 = 65024
// phase1 K1 [2][128*72]*2B = 36864 overlays [Khi..Vt] region.
#define SMEM_BYTES 65024

__global__ __launch_bounds__(512, 2) void sdpa_fused(
    const float* __restrict__ Qg, const float* __restrict__ Kg,
    const float* __restrict__ Vg, float* __restrict__ Og, float* __restrict__ Pg)
{
    const int i = blockIdx.x;
    const int g = i & 7;
    const int j = i >> 3;             // 0..63
    const int b = 2 * g + (j >> 5);
    const int jj = j & 31;
    const int qb = (j < 32) ? jj : (31 - jj);   // sum-balanced pairing
    const int q0 = qb * QB;

    const int tid = threadIdx.x;
    const int lane = tid & 63;
    const int wave = tid >> 6;        // 0..7
    const int wr = wave & 3;          // row band: rows wr*16..wr*16+15
    const int h  = wave >> 2;         // col half
    const int lo = lane & 15;
    const int hi = lane >> 4;
    const bool kStager = (wave < 4);
    const int stid = kStager ? tid : (tid - 256);
    const int sr = stid >> 4;
    const int sc_ = (stid & 15) * 4;
    const int vr = (stid >> 4) * 4;
    // phase-1 staging (all 512 threads): rows s1r+32*ii, col s1c
    const int s1r = tid >> 4;         // 0..31
    const int s1c = (tid & 15) * 4;

    __shared__ __align__(16) char smem[SMEM_BYTES];
    short (*Khi)[KT * KLD]  = reinterpret_cast<short (*)[KT * KLD]>(smem);            // [2]
    short (*Vt)[DIM * VLD]  = reinterpret_cast<short (*)[DIM * VLD]>(smem + 18432);   // [3]
    short (*Pb)[QB * PBLD]  = reinterpret_cast<short (*)[QB * PBLD]>(smem + 46080);   // [2]
    float (*lS)[QB]         = reinterpret_cast<float (*)[QB]>(smem + 64512);          // [2]
    short (*K1)[KT1 * KLD]  = reinterpret_cast<short (*)[KT1 * KLD]>(smem);           // [2] overlay

    const float* qB = Qg + (size_t)b * SEQ * DIM;
    const float* kB = Kg + (size_t)b * SEQ * DIM;
    const float* vB = Vg + (size_t)b * SEQ * DIM;

    bf16x8 qa0h, qa0l, qa1h, qa1l;
    {
        const float* qr = &qB[(size_t)(q0 + wr * 16 + lo) * DIM + hi * 8];
        split8(*(const f32x4*)qr,        *(const f32x4*)(qr + 4),  0.125f, qa0h, qa0l);
        split8(*(const f32x4*)(qr + 32), *(const f32x4*)(qr + 36), 0.125f, qa1h, qa1l);
    }

    const int nkt = qb + 1;

    // zero-fill coords: thread covers row zr, cols zc8..zc8+7 of a 64x64 tile
    const int zr = tid >> 3;
    const int zc8 = (tid & 7) * 8;
    float* zrow = &Pg[((size_t)(b * SEQ) + q0 + zr) * SEQ + zc8];
    const int zcnt = NQB - nkt;       // masked tiles: z = nkt + idx

    // ============ phase 1: l partial sums, KT1=128 per round ============
    float rl[4] = {0.f, 0.f, 0.f, 0.f};
    {
        const int nkt1 = (nkt + 1) >> 1;        // 128-wide rounds
        const int zpr = (zcnt + nkt1 - 1) / nkt1;   // zero tiles per round
        auto loadK1 = [&](f32x4* kp, int t) {
#pragma unroll
            for (int ii = 0; ii < 4; ++ii)
                kp[ii] = *(const f32x4*)&kB[(size_t)(t * KT1 + s1r + 32 * ii) * DIM + s1c];
        };
        auto stageK1 = [&](int buf, const f32x4* kp) {
#pragma unroll
            for (int ii = 0; ii < 4; ++ii) {
                short4v hh;
#pragma unroll
                for (int e = 0; e < 4; ++e) hh[e] = f2bf(kp[ii][e]);
                *(short4v*)&K1[buf][(s1r + 32 * ii) * KLD + s1c] = hh;
            }
        };
        f32x4 kp[4];
        loadK1(kp, 0);
        stageK1(0, kp);
        if (nkt1 > 1) loadK1(kp, 1);
        BAR();
        const int bandMax = q0 + wr * 16 + 15;  // wave-uniform
        for (int t = 0; t < nkt1; ++t) {
            const int cur = t & 1;
            if (t + 1 < nkt1) {
                stageK1(cur ^ 1, kp);
                if (t + 2 < nkt1) loadK1(kp, t + 2);
            }
            // interleaved zero-fill: stores fly across lgkm-only barriers
            {
                const int i0 = t * zpr;
                const int i1 = (i0 + zpr < zcnt) ? (i0 + zpr) : zcnt;
                const f32x4 zv = {0.f, 0.f, 0.f, 0.f};
                for (int idx = i0; idx < i1; ++idx) {
                    float* d = zrow + (nkt + idx) * KT;
                    *(f32x4*)d = zv;
                    *(f32x4*)(d + 4) = zv;
                }
            }
            const int base = t * KT1;
#pragma unroll
            for (int nn = 0; nn < 4; ++nn) {
                const int n = 4 * h + nn;       // col group 0..7 in the 128-tile
                const int cbase = base + 16 * n;
                if (cbase > bandMax) continue;  // wave-uniform skip
                bf16x8 kh0 = *(const bf16x8*)&K1[cur][(16 * n + lo) * KLD + hi * 8];
                bf16x8 kh1 = *(const bf16x8*)&K1[cur][(16 * n + lo) * KLD + 32 + hi * 8];
                f32x4 acc = {0.f, 0.f, 0.f, 0.f};
                __builtin_amdgcn_s_setprio(1);
                acc = __builtin_amdgcn_mfma_f32_16x16x32_bf16(qa0h, kh0, acc, 0, 0, 0);
                acc = __builtin_amdgcn_mfma_f32_16x16x32_bf16(qa1h, kh1, acc, 0, 0, 0);
                __builtin_amdgcn_s_setprio(0);
                if (cbase + 15 <= q0 + wr * 16) {   // fully unmasked (wave-uniform)
#pragma unroll
                    for (int jx = 0; jx < 4; ++jx) rl[jx] += __expf(acc[jx]);
                } else {
                    const int col = cbase + lo;
#pragma unroll
                    for (int jx = 0; jx < 4; ++jx)
                        if (col <= q0 + wr * 16 + hi * 4 + jx) rl[jx] += __expf(acc[jx]);
                }
            }
            BAR();
        }
    }
    // merge the two col-half partials -> il
#pragma unroll
    for (int m = 1; m <= 8; m <<= 1)
#pragma unroll
        for (int jx = 0; jx < 4; ++jx) rl[jx] += __shfl_xor(rl[jx], m, 16);
    if (lo == 0) {
#pragma unroll
        for (int jx = 0; jx < 4; ++jx)
            lS[h][wr * 16 + hi * 4 + jx] = rl[jx];
    }
    BAR();
    float il[4];
#pragma unroll
    for (int jx = 0; jx < 4; ++jx) {
        const int row = wr * 16 + hi * 4 + jx;
        il[jx] = 1.0f / (lS[0][row] + lS[1][row]);
    }
    BAR();   // all waves done reading lS before phase 2 overwrites smem

    // ===== phase 2: P = exp(S)*il direct-store + pipelined O = P*V =====
    const int n0 = 2 * h;
    f32x4 o2[2];
#pragma unroll
    for (int nn = 0; nn < 2; ++nn) { o2[nn][0] = 0.f; o2[nn][1] = 0.f; o2[nn][2] = 0.f; o2[nn][3] = 0.f; }

    float* prowBase = &Pg[((size_t)(b * SEQ) + q0 + wr * 16 + hi * 4) * SEQ + lo];

    auto loadK = [&](f32x4* kp, int kt) {
#pragma unroll
        for (int ii = 0; ii < 4; ++ii)
            kp[ii] = *(const f32x4*)&kB[(size_t)(kt * KT + sr + 16 * ii) * DIM + sc_];
    };
    auto loadV = [&](f32x4* vp, int kt) {
#pragma unroll
        for (int ii = 0; ii < 4; ++ii)
            vp[ii] = *(const f32x4*)&vB[(size_t)(kt * KT + vr + ii) * DIM + sc_];
    };
    auto stageKhi = [&](int buf, const f32x4* kp) {
#pragma unroll
        for (int ii = 0; ii < 4; ++ii) {
            short4v hh;
#pragma unroll
            for (int e = 0; e < 4; ++e) hh[e] = f2bf(kp[ii][e]);
            *(short4v*)&Khi[buf][(sr + 16 * ii) * KLD + sc_] = hh;
        }
    };
    auto stageVt = [&](int buf, const f32x4* vp) {
#pragma unroll
        for (int e = 0; e < 4; ++e) {
            short4v tv;
#pragma unroll
            for (int ii = 0; ii < 4; ++ii) tv[ii] = f2bf(vp[ii][e]);
            *(short4v*)&Vt[buf][(sc_ + e) * VLD + vr] = tv;
        }
    };

    {
        f32x4 kp[4], vp[4];
        if (kStager) {
            loadK(kp, 0); stageKhi(0, kp);
            if (nkt > 1) loadK(kp, 1);
        } else {
            loadV(vp, 0); stageVt(0, vp);
            if (nkt > 1) loadV(vp, 1);
        }
        BAR();

        int vstg = 1, vprev = 2;
        for (int kt = 0; kt < nkt; ++kt) {
            const int cur = kt & 1;
            const int pcur = kt & 1;
            if (kt + 1 < nkt) {
                if (kStager) {
                    stageKhi(cur ^ 1, kp);
                    if (kt + 2 < nkt) loadK(kp, kt + 2);
                } else {
                    stageVt(vstg, vp);
                    if (kt + 2 < nkt) loadV(vp, kt + 2);
                }
            }
            // ---- PV(kt-1): partner-wave Pb/Vt ordered by previous BAR ----
            if (kt > 0) {
                bf16x8 pa0 = *(const bf16x8*)&Pb[pcur ^ 1][(wr * 16 + lo) * PBLD + hi * 8];
                bf16x8 pa1 = *(const bf16x8*)&Pb[pcur ^ 1][(wr * 16 + lo) * PBLD + 32 + hi * 8];
                __builtin_amdgcn_s_setprio(1);
#pragma unroll
                for (int nn = 0; nn < 2; ++nn) {
                    const int n = n0 + nn;
                    bf16x8 vb0 = *(const bf16x8*)&Vt[vprev][(16 * n + lo) * VLD + hi * 8];
                    bf16x8 vb1 = *(const bf16x8*)&Vt[vprev][(16 * n + lo) * VLD + 32 + hi * 8];
                    o2[nn] = __builtin_amdgcn_mfma_f32_16x16x32_bf16(pa0, vb0, o2[nn], 0, 0, 0);
                    o2[nn] = __builtin_amdgcn_mfma_f32_16x16x32_bf16(pa1, vb1, o2[nn], 0, 0, 0);
                }
                __builtin_amdgcn_s_setprio(0);
            }
            // ---- QKT(kt) (Q-side compensated): P = exp(S)*il ----
#pragma unroll
            for (int nn = 0; nn < 2; ++nn) {
                const int n = n0 + nn;
                const bool fm = (kt == qb) && (n > wr);   // wave-uniform
                f32x4 acc = {0.f, 0.f, 0.f, 0.f};
                if (!fm) {
                    bf16x8 kh0 = *(const bf16x8*)&Khi[cur][(16 * n + lo) * KLD + hi * 8];
                    bf16x8 kh1 = *(const bf16x8*)&Khi[cur][(16 * n + lo) * KLD + 32 + hi * 8];
                    __builtin_amdgcn_s_setprio(1);
                    acc = __builtin_amdgcn_mfma_f32_16x16x32_bf16(qa0h, kh0, acc, 0, 0, 0);
                    acc = __builtin_amdgcn_mfma_f32_16x16x32_bf16(qa1h, kh1, acc, 0, 0, 0);
                    acc = __builtin_amdgcn_mfma_f32_16x16x32_bf16(qa0l, kh0, acc, 0, 0, 0);
                    acc = __builtin_amdgcn_mfma_f32_16x16x32_bf16(qa1l, kh1, acc, 0, 0, 0);
                    __builtin_amdgcn_s_setprio(0);
                }
                const int col = 16 * n + lo;
                float* pcol = prowBase + kt * KT + 16 * n;
#pragma unroll
                for (int jx = 0; jx < 4; ++jx) {
                    const int row = wr * 16 + hi * 4 + jx;
                    const float p = (!fm && (kt < qb || col <= row)) ? __expf(acc[jx]) * il[jx] : 0.f;
                    pcol[(size_t)jx * SEQ] = p;
                    Pb[pcur][row * PBLD + col] = f2bf(p);
                }
            }
            BAR();
            vprev = (vprev == 2) ? 0 : vprev + 1;
            vstg  = (vstg  == 2) ? 0 : vstg  + 1;
        }
        // ---- epilogue PV(nkt-1): ordered by the loop's final BAR ----
        {
            const int pl = (nkt - 1) & 1;
            const int vl = (nkt - 1) % 3;
            bf16x8 pa0 = *(const bf16x8*)&Pb[pl][(wr * 16 + lo) * PBLD + hi * 8];
            bf16x8 pa1 = *(const bf16x8*)&Pb[pl][(wr * 16 + lo) * PBLD + 32 + hi * 8];
#pragma unroll
            for (int nn = 0; nn < 2; ++nn) {
                const int n = n0 + nn;
                bf16x8 vb0 = *(const bf16x8*)&Vt[vl][(16 * n + lo) * VLD + hi * 8];
                bf16x8 vb1 = *(const bf16x8*)&Vt[vl][(16 * n + lo) * VLD + 32 + hi * 8];
                o2[nn] = __builtin_amdgcn_mfma_f32_16x16x32_bf16(pa0, vb0, o2[nn], 0, 0, 0);
                o2[nn] = __builtin_amdgcn_mfma_f32_16x16x32_bf16(pa1, vb1, o2[nn], 0, 0, 0);
            }
        }
    }

    // ---- O (already normalized; own col half), fp32 ----
    {
        float* og = &Og[((size_t)(b * SEQ) + q0 + wr * 16 + hi * 4) * DIM + lo];
#pragma unroll
        for (int jx = 0; jx < 4; ++jx)
#pragma unroll
            for (int nn = 0; nn < 2; ++nn)
                og[jx * DIM + (n0 + nn) * 16] = o2[nn][jx];
    }
}

extern "C" void kernel_launch(void* const* d_in, const int* in_sizes, int n_in,
                              void* d_out, int out_size, void* d_ws, size_t ws_size,
                              hipStream_t stream) {
    const float* q = (const float*)d_in[0];
    const float* k = (const float*)d_in[1];
    const float* v = (const float*)d_in[2];
    float* out  = (float*)d_out;                        // [B,T,D] fp32
    float* smqk = out + (size_t)BATCHES * SEQ * DIM;    // [B,T,T] fp32

    sdpa_fused<<<NQB * BATCHES, 512, 0, stream>>>(q, k, v, out, smqk);
}

// Round 19
// 96.715 us; speedup vs baseline: 1.0373x; 1.0373x over previous
//
#include <hip/hip_runtime.h>
#include <hip/hip_bf16.h>

// SDPA, causal, b=16 t=2048 d=64. Outputs FP32: d_out = [ out | sm_qk ].
// R19 = R17 + coalesced store path:
//  - P tile kept fp32 in LDS (Pf[2], replaces bf16 Pb); global P store is one
//    256B fully-contiguous burst per row (8 rows/wave), pipelined one tile
//    behind (same slot as PV(kt-1)). PV A-frag reads Pf[prev] + cvt.
//  - zero-fill tail emits 256B contiguous bursts (was 16B@32B-stride).
// R17 base: 8-wave blocks; phase-1 KT1=128 via LDS overlay; T15 pipeline;
// role-split staging; Q-side-compensated QK^T; lgkm-only barriers;
// pairing (c, 31-c).

#define BATCHES 16
#define SEQ 2048
#define DIM 64
#define QB 64
#define KT 64
#define KT1 128
#define NQB (SEQ / QB) /* 32 */
#define KLD 72
#define VLD 72
#define PFLD 68

#define BAR() do { asm volatile("s_waitcnt lgkmcnt(0)" ::: "memory"); \
                   __builtin_amdgcn_s_barrier(); } while (0)

typedef __attribute__((ext_vector_type(8))) short bf16x8;
typedef __attribute__((ext_vector_type(4))) short short4v;
typedef __attribute__((ext_vector_type(4))) float f32x4;

static __device__ __forceinline__ short f2bf(float f) {
    return __builtin_bit_cast(short, __float2bfloat16(f));
}
static __device__ __forceinline__ float bf2f(short s) {
    unsigned int u = ((unsigned int)(unsigned short)s) << 16;
    return __builtin_bit_cast(float, u);
}
static __device__ __forceinline__ void split8(f32x4 a, f32x4 b, float sc,
                                              bf16x8& hh, bf16x8& ll) {
#pragma unroll
    for (int e = 0; e < 4; ++e) {
        float x = a[e] * sc; short hb = f2bf(x);
        hh[e] = hb; ll[e] = f2bf(x - bf2f(hb));
    }
#pragma unroll
    for (int e = 0; e < 4; ++e) {
        float x = b[e] * sc; short hb = f2bf(x);
        hh[4 + e] = hb; ll[4 + e] = f2bf(x - bf2f(hb));
    }
}

// LDS (bytes): Khi 18432 @0 | Vt 27648 @18432 | Pf 34816 @46080 | lS 512 @80896
// = 81408 total (<= 81920 for 2 blocks/CU). Phase-1 K1[2] 36864 overlays @0.
#define SMEM_BYTES 81408

__global__ __launch_bounds__(512, 2) void sdpa_fused(
    const float* __restrict__ Qg, const float* __restrict__ Kg,
    const float* __restrict__ Vg, float* __restrict__ Og, float* __restrict__ Pg)
{
    const int i = blockIdx.x;
    const int g = i & 7;
    const int j = i >> 3;             // 0..63
    const int b = 2 * g + (j >> 5);
    const int jj = j & 31;
    const int qb = (j < 32) ? jj : (31 - jj);   // sum-balanced pairing
    const int q0 = qb * QB;

    const int tid = threadIdx.x;
    const int lane = tid & 63;
    const int wave = tid >> 6;        // 0..7
    const int wr = wave & 3;          // row band: rows wr*16..wr*16+15
    const int h  = wave >> 2;         // col half
    const int lo = lane & 15;
    const int hi = lane >> 4;
    const bool kStager = (wave < 4);
    const int stid = kStager ? tid : (tid - 256);
    const int sr = stid >> 4;
    const int sc_ = (stid & 15) * 4;
    const int vr = (stid >> 4) * 4;
    // phase-1 staging (all 512 threads): rows s1r+32*ii, col s1c
    const int s1r = tid >> 4;         // 0..31
    const int s1c = (tid & 15) * 4;

    __shared__ __align__(16) char smem[SMEM_BYTES];
    short (*Khi)[KT * KLD]  = reinterpret_cast<short (*)[KT * KLD]>(smem);            // [2]
    short (*Vt)[DIM * VLD]  = reinterpret_cast<short (*)[DIM * VLD]>(smem + 18432);   // [3]
    float (*Pf)[QB * PFLD]  = reinterpret_cast<float (*)[QB * PFLD]>(smem + 46080);   // [2]
    float (*lS)[QB]         = reinterpret_cast<float (*)[QB]>(smem + 80896);          // [2]
    short (*K1)[KT1 * KLD]  = reinterpret_cast<short (*)[KT1 * KLD]>(smem);           // [2] overlay

    const float* qB = Qg + (size_t)b * SEQ * DIM;
    const float* kB = Kg + (size_t)b * SEQ * DIM;
    const float* vB = Vg + (size_t)b * SEQ * DIM;

    bf16x8 qa0h, qa0l, qa1h, qa1l;
    {
        const float* qr = &qB[(size_t)(q0 + wr * 16 + lo) * DIM + hi * 8];
        split8(*(const f32x4*)qr,        *(const f32x4*)(qr + 4),  0.125f, qa0h, qa0l);
        split8(*(const f32x4*)(qr + 32), *(const f32x4*)(qr + 36), 0.125f, qa1h, qa1l);
    }

    const int nkt = qb + 1;

    // ============ phase 1: l partial sums, KT1=128 per round ============
    float rl[4] = {0.f, 0.f, 0.f, 0.f};
    {
        const int nkt1 = (nkt + 1) >> 1;        // 128-wide rounds
        auto loadK1 = [&](f32x4* kp, int t) {
#pragma unroll
            for (int ii = 0; ii < 4; ++ii)
                kp[ii] = *(const f32x4*)&kB[(size_t)(t * KT1 + s1r + 32 * ii) * DIM + s1c];
        };
        auto stageK1 = [&](int buf, const f32x4* kp) {
#pragma unroll
            for (int ii = 0; ii < 4; ++ii) {
                short4v hh;
#pragma unroll
                for (int e = 0; e < 4; ++e) hh[e] = f2bf(kp[ii][e]);
                *(short4v*)&K1[buf][(s1r + 32 * ii) * KLD + s1c] = hh;
            }
        };
        f32x4 kp[4];
        loadK1(kp, 0);
        stageK1(0, kp);
        if (nkt1 > 1) loadK1(kp, 1);
        BAR();
        const int bandMax = q0 + wr * 16 + 15;  // wave-uniform
        for (int t = 0; t < nkt1; ++t) {
            const int cur = t & 1;
            if (t + 1 < nkt1) {
                stageK1(cur ^ 1, kp);
                if (t + 2 < nkt1) loadK1(kp, t + 2);
            }
            const int base = t * KT1;
#pragma unroll
            for (int nn = 0; nn < 4; ++nn) {
                const int n = 4 * h + nn;       // col group 0..7 in the 128-tile
                const int cbase = base + 16 * n;
                if (cbase > bandMax) continue;  // wave-uniform skip
                bf16x8 kh0 = *(const bf16x8*)&K1[cur][(16 * n + lo) * KLD + hi * 8];
                bf16x8 kh1 = *(const bf16x8*)&K1[cur][(16 * n + lo) * KLD + 32 + hi * 8];
                f32x4 acc = {0.f, 0.f, 0.f, 0.f};
                __builtin_amdgcn_s_setprio(1);
                acc = __builtin_amdgcn_mfma_f32_16x16x32_bf16(qa0h, kh0, acc, 0, 0, 0);
                acc = __builtin_amdgcn_mfma_f32_16x16x32_bf16(qa1h, kh1, acc, 0, 0, 0);
                __builtin_amdgcn_s_setprio(0);
                if (cbase + 15 <= q0 + wr * 16) {   // fully unmasked (wave-uniform)
#pragma unroll
                    for (int jx = 0; jx < 4; ++jx) rl[jx] += __expf(acc[jx]);
                } else {
                    const int col = cbase + lo;
#pragma unroll
                    for (int jx = 0; jx < 4; ++jx)
                        if (col <= q0 + wr * 16 + hi * 4 + jx) rl[jx] += __expf(acc[jx]);
                }
            }
            BAR();
        }
    }
    // merge the two col-half partials -> il
#pragma unroll
    for (int m = 1; m <= 8; m <<= 1)
#pragma unroll
        for (int jx = 0; jx < 4; ++jx) rl[jx] += __shfl_xor(rl[jx], m, 16);
    if (lo == 0) {
#pragma unroll
        for (int jx = 0; jx < 4; ++jx)
            lS[h][wr * 16 + hi * 4 + jx] = rl[jx];
    }
    BAR();
    float il[4];
#pragma unroll
    for (int jx = 0; jx < 4; ++jx) {
        const int row = wr * 16 + hi * 4 + jx;
        il[jx] = 1.0f / (lS[0][row] + lS[1][row]);
    }
    BAR();   // all waves done reading lS before phase 2 overwrites smem

    // ===== phase 2: P -> Pf (fp32 LDS), coalesced row-store + PV pipelined ===
    const int n0 = 2 * h;
    f32x4 o2[2];
#pragma unroll
    for (int nn = 0; nn < 2; ++nn) { o2[nn][0] = 0.f; o2[nn][1] = 0.f; o2[nn][2] = 0.f; o2[nn][3] = 0.f; }

    auto loadK = [&](f32x4* kp, int kt) {
#pragma unroll
        for (int ii = 0; ii < 4; ++ii)
            kp[ii] = *(const f32x4*)&kB[(size_t)(kt * KT + sr + 16 * ii) * DIM + sc_];
    };
    auto loadV = [&](f32x4* vp, int kt) {
#pragma unroll
        for (int ii = 0; ii < 4; ++ii)
            vp[ii] = *(const f32x4*)&vB[(size_t)(kt * KT + vr + ii) * DIM + sc_];
    };
    auto stageKhi = [&](int buf, const f32x4* kp) {
#pragma unroll
        for (int ii = 0; ii < 4; ++ii) {
            short4v hh;
#pragma unroll
            for (int e = 0; e < 4; ++e) hh[e] = f2bf(kp[ii][e]);
            *(short4v*)&Khi[buf][(sr + 16 * ii) * KLD + sc_] = hh;
        }
    };
    auto stageVt = [&](int buf, const f32x4* vp) {
#pragma unroll
        for (int e = 0; e < 4; ++e) {
            short4v tv;
#pragma unroll
            for (int ii = 0; ii < 4; ++ii) tv[ii] = f2bf(vp[ii][e]);
            *(short4v*)&Vt[buf][(sc_ + e) * VLD + vr] = tv;
        }
    };
    // coalesced P row-store: 8 rows/wave, one 256B contiguous burst per row
    auto rowStore = [&](int pbuf, int kt) {
        float* dstb = &Pg[((size_t)(b * SEQ) + q0 + wave * 8) * SEQ + kt * KT + lane];
#pragma unroll
        for (int rr = 0; rr < 8; ++rr)
            dstb[(size_t)rr * SEQ] = Pf[pbuf][(wave * 8 + rr) * PFLD + lane];
    };
    // PV from Pf[pbuf] (fp32 -> bf16 frags) against Vt[vbuf]
    auto pvStep = [&](int pbuf, int vbuf) {
        const float* pr = &Pf[pbuf][(wr * 16 + lo) * PFLD + hi * 8];
        f32x4 a = *(const f32x4*)pr, c2 = *(const f32x4*)(pr + 4);
        f32x4 d = *(const f32x4*)(pr + 32), e2 = *(const f32x4*)(pr + 36);
        bf16x8 pa0, pa1;
#pragma unroll
        for (int e = 0; e < 4; ++e) {
            pa0[e] = f2bf(a[e]); pa0[4 + e] = f2bf(c2[e]);
            pa1[e] = f2bf(d[e]); pa1[4 + e] = f2bf(e2[e]);
        }
        __builtin_amdgcn_s_setprio(1);
#pragma unroll
        for (int nn = 0; nn < 2; ++nn) {
            const int n = n0 + nn;
            bf16x8 vb0 = *(const bf16x8*)&Vt[vbuf][(16 * n + lo) * VLD + hi * 8];
            bf16x8 vb1 = *(const bf16x8*)&Vt[vbuf][(16 * n + lo) * VLD + 32 + hi * 8];
            o2[nn] = __builtin_amdgcn_mfma_f32_16x16x32_bf16(pa0, vb0, o2[nn], 0, 0, 0);
            o2[nn] = __builtin_amdgcn_mfma_f32_16x16x32_bf16(pa1, vb1, o2[nn], 0, 0, 0);
        }
        __builtin_amdgcn_s_setprio(0);
    };

    {
        f32x4 kp[4], vp[4];
        if (kStager) {
            loadK(kp, 0); stageKhi(0, kp);
            if (nkt > 1) loadK(kp, 1);
        } else {
            loadV(vp, 0); stageVt(0, vp);
            if (nkt > 1) loadV(vp, 1);
        }
        BAR();

        int vstg = 1, vprev = 2;
        for (int kt = 0; kt < nkt; ++kt) {
            const int cur = kt & 1;
            const int pcur = kt & 1;
            if (kt + 1 < nkt) {
                if (kStager) {
                    stageKhi(cur ^ 1, kp);
                    if (kt + 2 < nkt) loadK(kp, kt + 2);
                } else {
                    stageVt(vstg, vp);
                    if (kt + 2 < nkt) loadV(vp, kt + 2);
                }
            }
            // ---- tile kt-1: coalesced row-store + PV (inputs ready at start)
            if (kt > 0) {
                rowStore(pcur ^ 1, kt - 1);
                pvStep(pcur ^ 1, vprev);
            }
            // ---- QKT(kt) (Q-side compensated): P = exp(S)*il -> Pf[pcur] ----
#pragma unroll
            for (int nn = 0; nn < 2; ++nn) {
                const int n = n0 + nn;
                const bool fm = (kt == qb) && (n > wr);   // wave-uniform
                f32x4 acc = {0.f, 0.f, 0.f, 0.f};
                if (!fm) {
                    bf16x8 kh0 = *(const bf16x8*)&Khi[cur][(16 * n + lo) * KLD + hi * 8];
                    bf16x8 kh1 = *(const bf16x8*)&Khi[cur][(16 * n + lo) * KLD + 32 + hi * 8];
                    __builtin_amdgcn_s_setprio(1);
                    acc = __builtin_amdgcn_mfma_f32_16x16x32_bf16(qa0h, kh0, acc, 0, 0, 0);
                    acc = __builtin_amdgcn_mfma_f32_16x16x32_bf16(qa1h, kh1, acc, 0, 0, 0);
                    acc = __builtin_amdgcn_mfma_f32_16x16x32_bf16(qa0l, kh0, acc, 0, 0, 0);
                    acc = __builtin_amdgcn_mfma_f32_16x16x32_bf16(qa1l, kh1, acc, 0, 0, 0);
                    __builtin_amdgcn_s_setprio(0);
                }
                const int col = 16 * n + lo;
#pragma unroll
                for (int jx = 0; jx < 4; ++jx) {
                    const int row = wr * 16 + hi * 4 + jx;
                    const float p = (!fm && (kt < qb || col <= row)) ? __expf(acc[jx]) * il[jx] : 0.f;
                    Pf[pcur][row * PFLD + col] = p;
                }
            }
            BAR();
            vprev = (vprev == 2) ? 0 : vprev + 1;
            vstg  = (vstg  == 2) ? 0 : vstg  + 1;
        }
        // ---- epilogue: tile nkt-1 store + PV (after the loop's final BAR) ----
        {
            const int pl = (nkt - 1) & 1;
            const int vl = (nkt - 1) % 3;
            rowStore(pl, nkt - 1);
            pvStep(pl, vl);
        }
    }

    // ---- zero-fill fully-masked tiles: 256B contiguous bursts ----
    {
        const int r16 = tid >> 4;           // 0..31
        const int c4 = (tid & 15) * 4;
        float* row0 = &Pg[((size_t)(b * SEQ) + q0 + r16) * SEQ + c4];
        float* row1 = &Pg[((size_t)(b * SEQ) + q0 + 32 + r16) * SEQ + c4];
        const f32x4 z = {0.f, 0.f, 0.f, 0.f};
        for (int cb = nkt * KT; cb < SEQ; cb += KT) {
            *(f32x4*)&row0[cb] = z;
            *(f32x4*)&row1[cb] = z;
        }
    }
    // ---- O (already normalized; own col half), fp32 ----
    {
        float* og = &Og[((size_t)(b * SEQ) + q0 + wr * 16 + hi * 4) * DIM + lo];
#pragma unroll
        for (int jx = 0; jx < 4; ++jx)
#pragma unroll
            for (int nn = 0; nn < 2; ++nn)
                og[jx * DIM + (n0 + nn) * 16] = o2[nn][jx];
    }
}

extern "C" void kernel_launch(void* const* d_in, const int* in_sizes, int n_in,
                              void* d_out, int out_size, void* d_ws, size_t ws_size,
                              hipStream_t stream) {
    const float* q = (const float*)d_in[0];
    const float* k = (const float*)d_in[1];
    const float* v = (const float*)d_in[2];
    float* out  = (float*)d_out;                        // [B,T,D] fp32
    float* smqk = out + (size_t)BATCHES * SEQ * DIM;    // [B,T,T] fp32

    sdpa_fused<<<NQB * BATCHES, 512, 0, stream>>>(q, k, v, out, smqk);
}

// Round 20
// 95.496 us; speedup vs baseline: 1.0506x; 1.0128x over previous
//
#include <hip/hip_runtime.h>
#include <hip/hip_bf16.h>

// SDPA, causal, b=16 t=2048 d=64. Outputs FP32: d_out = [ out | sm_qk ].
// R20 = R19 + MIRROR-BAND ZERO-FILL: block (b,qb) zeros the masked tiles of
// band (31-qb) of its own batch -- exactly qb tiles over qb+1 phase-2 rounds,
// ONE tile (2 store instrs/thread) per round. Stores are issued younger than
// the round's prefetch loads and retire a full round before the next vmcnt
// wait -> no in-order-vmcnt pollution (R11/R18's burst failure mode).
// End-of-kernel zero tail REMOVED (the ~15us serialized drain).
// R19 base: 8-wave blocks; phase-1 KT1=128 LDS overlay; T15 pipeline;
// role-split staging; Q-side-compensated QK^T; fp32 Pf + coalesced 256B
// row-stores; lgkm-only barriers; pairing (c, 31-c).

#define BATCHES 16
#define SEQ 2048
#define DIM 64
#define QB 64
#define KT 64
#define KT1 128
#define NQB (SEQ / QB) /* 32 */
#define KLD 72
#define VLD 72
#define PFLD 68

#define BAR() do { asm volatile("s_waitcnt lgkmcnt(0)" ::: "memory"); \
                   __builtin_amdgcn_s_barrier(); } while (0)

typedef __attribute__((ext_vector_type(8))) short bf16x8;
typedef __attribute__((ext_vector_type(4))) short short4v;
typedef __attribute__((ext_vector_type(4))) float f32x4;

static __device__ __forceinline__ short f2bf(float f) {
    return __builtin_bit_cast(short, __float2bfloat16(f));
}
static __device__ __forceinline__ float bf2f(short s) {
    unsigned int u = ((unsigned int)(unsigned short)s) << 16;
    return __builtin_bit_cast(float, u);
}
static __device__ __forceinline__ void split8(f32x4 a, f32x4 b, float sc,
                                              bf16x8& hh, bf16x8& ll) {
#pragma unroll
    for (int e = 0; e < 4; ++e) {
        float x = a[e] * sc; short hb = f2bf(x);
        hh[e] = hb; ll[e] = f2bf(x - bf2f(hb));
    }
#pragma unroll
    for (int e = 0; e < 4; ++e) {
        float x = b[e] * sc; short hb = f2bf(x);
        hh[4 + e] = hb; ll[4 + e] = f2bf(x - bf2f(hb));
    }
}

// LDS (bytes): Khi 18432 @0 | Vt 27648 @18432 | Pf 34816 @46080 | lS 512 @80896
// = 81408 total (2 blocks/CU). Phase-1 K1[2] 36864 overlays @0.
#define SMEM_BYTES 81408

__global__ __launch_bounds__(512, 2) void sdpa_fused(
    const float* __restrict__ Qg, const float* __restrict__ Kg,
    const float* __restrict__ Vg, float* __restrict__ Og, float* __restrict__ Pg)
{
    const int i = blockIdx.x;
    const int g = i & 7;
    const int j = i >> 3;             // 0..63
    const int b = 2 * g + (j >> 5);
    const int jj = j & 31;
    const int qb = (j < 32) ? jj : (31 - jj);   // sum-balanced pairing
    const int q0 = qb * QB;

    const int tid = threadIdx.x;
    const int lane = tid & 63;
    const int wave = tid >> 6;        // 0..7
    const int wr = wave & 3;          // row band: rows wr*16..wr*16+15
    const int h  = wave >> 2;         // col half
    const int lo = lane & 15;
    const int hi = lane >> 4;
    const bool kStager = (wave < 4);
    const int stid = kStager ? tid : (tid - 256);
    const int sr = stid >> 4;
    const int sc_ = (stid & 15) * 4;
    const int vr = (stid >> 4) * 4;
    // phase-1 staging (all 512 threads): rows s1r+32*ii, col s1c
    const int s1r = tid >> 4;         // 0..31
    const int s1c = (tid & 15) * 4;

    __shared__ __align__(16) char smem[SMEM_BYTES];
    short (*Khi)[KT * KLD]  = reinterpret_cast<short (*)[KT * KLD]>(smem);            // [2]
    short (*Vt)[DIM * VLD]  = reinterpret_cast<short (*)[DIM * VLD]>(smem + 18432);   // [3]
    float (*Pf)[QB * PFLD]  = reinterpret_cast<float (*)[QB * PFLD]>(smem + 46080);   // [2]
    float (*lS)[QB]         = reinterpret_cast<float (*)[QB]>(smem + 80896);          // [2]
    short (*K1)[KT1 * KLD]  = reinterpret_cast<short (*)[KT1 * KLD]>(smem);           // [2] overlay

    const float* qB = Qg + (size_t)b * SEQ * DIM;
    const float* kB = Kg + (size_t)b * SEQ * DIM;
    const float* vB = Vg + (size_t)b * SEQ * DIM;

    bf16x8 qa0h, qa0l, qa1h, qa1l;
    {
        const float* qr = &qB[(size_t)(q0 + wr * 16 + lo) * DIM + hi * 8];
        split8(*(const f32x4*)qr,        *(const f32x4*)(qr + 4),  0.125f, qa0h, qa0l);
        split8(*(const f32x4*)(qr + 32), *(const f32x4*)(qr + 36), 0.125f, qa1h, qa1l);
    }

    const int nkt = qb + 1;

    // mirror-band zero-fill coords: band (31-qb) of our own batch, tile 32-qb+kt
    const int r16z = tid >> 4;        // 0..31
    const int c4z = (tid & 15) * 4;
    float* zrow0 = &Pg[((size_t)(b * SEQ) + (NQB - 1 - qb) * QB + r16z) * SEQ + c4z];
    float* zrow1 = zrow0 + (size_t)32 * SEQ;

    // ============ phase 1: l partial sums, KT1=128 per round ============
    float rl[4] = {0.f, 0.f, 0.f, 0.f};
    {
        const int nkt1 = (nkt + 1) >> 1;        // 128-wide rounds
        auto loadK1 = [&](f32x4* kp, int t) {
#pragma unroll
            for (int ii = 0; ii < 4; ++ii)
                kp[ii] = *(const f32x4*)&kB[(size_t)(t * KT1 + s1r + 32 * ii) * DIM + s1c];
        };
        auto stageK1 = [&](int buf, const f32x4* kp) {
#pragma unroll
            for (int ii = 0; ii < 4; ++ii) {
                short4v hh;
#pragma unroll
                for (int e = 0; e < 4; ++e) hh[e] = f2bf(kp[ii][e]);
                *(short4v*)&K1[buf][(s1r + 32 * ii) * KLD + s1c] = hh;
            }
        };
        f32x4 kp[4];
        loadK1(kp, 0);
        stageK1(0, kp);
        if (nkt1 > 1) loadK1(kp, 1);
        BAR();
        const int bandMax = q0 + wr * 16 + 15;  // wave-uniform
        for (int t = 0; t < nkt1; ++t) {
            const int cur = t & 1;
            if (t + 1 < nkt1) {
                stageK1(cur ^ 1, kp);
                if (t + 2 < nkt1) loadK1(kp, t + 2);
            }
            const int base = t * KT1;
#pragma unroll
            for (int nn = 0; nn < 4; ++nn) {
                const int n = 4 * h + nn;       // col group 0..7 in the 128-tile
                const int cbase = base + 16 * n;
                if (cbase > bandMax) continue;  // wave-uniform skip
                bf16x8 kh0 = *(const bf16x8*)&K1[cur][(16 * n + lo) * KLD + hi * 8];
                bf16x8 kh1 = *(const bf16x8*)&K1[cur][(16 * n + lo) * KLD + 32 + hi * 8];
                f32x4 acc = {0.f, 0.f, 0.f, 0.f};
                __builtin_amdgcn_s_setprio(1);
                acc = __builtin_amdgcn_mfma_f32_16x16x32_bf16(qa0h, kh0, acc, 0, 0, 0);
                acc = __builtin_amdgcn_mfma_f32_16x16x32_bf16(qa1h, kh1, acc, 0, 0, 0);
                __builtin_amdgcn_s_setprio(0);
                if (cbase + 15 <= q0 + wr * 16) {   // fully unmasked (wave-uniform)
#pragma unroll
                    for (int jx = 0; jx < 4; ++jx) rl[jx] += __expf(acc[jx]);
                } else {
                    const int col = cbase + lo;
#pragma unroll
                    for (int jx = 0; jx < 4; ++jx)
                        if (col <= q0 + wr * 16 + hi * 4 + jx) rl[jx] += __expf(acc[jx]);
                }
            }
            BAR();
        }
    }
    // merge the two col-half partials -> il
#pragma unroll
    for (int m = 1; m <= 8; m <<= 1)
#pragma unroll
        for (int jx = 0; jx < 4; ++jx) rl[jx] += __shfl_xor(rl[jx], m, 16);
    if (lo == 0) {
#pragma unroll
        for (int jx = 0; jx < 4; ++jx)
            lS[h][wr * 16 + hi * 4 + jx] = rl[jx];
    }
    BAR();
    float il[4];
#pragma unroll
    for (int jx = 0; jx < 4; ++jx) {
        const int row = wr * 16 + hi * 4 + jx;
        il[jx] = 1.0f / (lS[0][row] + lS[1][row]);
    }
    BAR();   // all waves done reading lS before phase 2 overwrites smem

    // ===== phase 2: P -> Pf (fp32 LDS), coalesced row-store + PV pipelined ===
    const int n0 = 2 * h;
    f32x4 o2[2];
#pragma unroll
    for (int nn = 0; nn < 2; ++nn) { o2[nn][0] = 0.f; o2[nn][1] = 0.f; o2[nn][2] = 0.f; o2[nn][3] = 0.f; }

    auto loadK = [&](f32x4* kp, int kt) {
#pragma unroll
        for (int ii = 0; ii < 4; ++ii)
            kp[ii] = *(const f32x4*)&kB[(size_t)(kt * KT + sr + 16 * ii) * DIM + sc_];
    };
    auto loadV = [&](f32x4* vp, int kt) {
#pragma unroll
        for (int ii = 0; ii < 4; ++ii)
            vp[ii] = *(const f32x4*)&vB[(size_t)(kt * KT + vr + ii) * DIM + sc_];
    };
    auto stageKhi = [&](int buf, const f32x4* kp) {
#pragma unroll
        for (int ii = 0; ii < 4; ++ii) {
            short4v hh;
#pragma unroll
            for (int e = 0; e < 4; ++e) hh[e] = f2bf(kp[ii][e]);
            *(short4v*)&Khi[buf][(sr + 16 * ii) * KLD + sc_] = hh;
        }
    };
    auto stageVt = [&](int buf, const f32x4* vp) {
#pragma unroll
        for (int e = 0; e < 4; ++e) {
            short4v tv;
#pragma unroll
            for (int ii = 0; ii < 4; ++ii) tv[ii] = f2bf(vp[ii][e]);
            *(short4v*)&Vt[buf][(sc_ + e) * VLD + vr] = tv;
        }
    };
    // coalesced P row-store: 8 rows/wave, one 256B contiguous burst per row
    auto rowStore = [&](int pbuf, int kt) {
        float* dstb = &Pg[((size_t)(b * SEQ) + q0 + wave * 8) * SEQ + kt * KT + lane];
#pragma unroll
        for (int rr = 0; rr < 8; ++rr)
            dstb[(size_t)rr * SEQ] = Pf[pbuf][(wave * 8 + rr) * PFLD + lane];
    };
    // PV from Pf[pbuf] (fp32 -> bf16 frags) against Vt[vbuf]
    auto pvStep = [&](int pbuf, int vbuf) {
        const float* pr = &Pf[pbuf][(wr * 16 + lo) * PFLD + hi * 8];
        f32x4 a = *(const f32x4*)pr, c2 = *(const f32x4*)(pr + 4);
        f32x4 d = *(const f32x4*)(pr + 32), e2 = *(const f32x4*)(pr + 36);
        bf16x8 pa0, pa1;
#pragma unroll
        for (int e = 0; e < 4; ++e) {
            pa0[e] = f2bf(a[e]); pa0[4 + e] = f2bf(c2[e]);
            pa1[e] = f2bf(d[e]); pa1[4 + e] = f2bf(e2[e]);
        }
        __builtin_amdgcn_s_setprio(1);
#pragma unroll
        for (int nn = 0; nn < 2; ++nn) {
            const int n = n0 + nn;
            bf16x8 vb0 = *(const bf16x8*)&Vt[vbuf][(16 * n + lo) * VLD + hi * 8];
            bf16x8 vb1 = *(const bf16x8*)&Vt[vbuf][(16 * n + lo) * VLD + 32 + hi * 8];
            o2[nn] = __builtin_amdgcn_mfma_f32_16x16x32_bf16(pa0, vb0, o2[nn], 0, 0, 0);
            o2[nn] = __builtin_amdgcn_mfma_f32_16x16x32_bf16(pa1, vb1, o2[nn], 0, 0, 0);
        }
        __builtin_amdgcn_s_setprio(0);
    };

    {
        f32x4 kp[4], vp[4];
        if (kStager) {
            loadK(kp, 0); stageKhi(0, kp);
            if (nkt > 1) loadK(kp, 1);
        } else {
            loadV(vp, 0); stageVt(0, vp);
            if (nkt > 1) loadV(vp, 1);
        }
        BAR();

        int vstg = 1, vprev = 2;
        for (int kt = 0; kt < nkt; ++kt) {
            const int cur = kt & 1;
            const int pcur = kt & 1;
            // ---- mirror-band zero tile (1/round, kt<qb): 2 stores/thread,
            //      issued YOUNGER than last round's loads -> no vmcnt stall ----
            if (kt < qb) {
                const int zt = (NQB - qb) + kt;     // tile 32-qb+kt of band 31-qb
                const f32x4 zv = {0.f, 0.f, 0.f, 0.f};
                *(f32x4*)&zrow0[zt * KT] = zv;
                *(f32x4*)&zrow1[zt * KT] = zv;
            }
            if (kt + 1 < nkt) {
                if (kStager) {
                    stageKhi(cur ^ 1, kp);
                    if (kt + 2 < nkt) loadK(kp, kt + 2);
                } else {
                    stageVt(vstg, vp);
                    if (kt + 2 < nkt) loadV(vp, kt + 2);
                }
            }
            // ---- tile kt-1: coalesced row-store + PV (inputs ready at start)
            if (kt > 0) {
                rowStore(pcur ^ 1, kt - 1);
                pvStep(pcur ^ 1, vprev);
            }
            // ---- QKT(kt) (Q-side compensated): P = exp(S)*il -> Pf[pcur] ----
#pragma unroll
            for (int nn = 0; nn < 2; ++nn) {
                const int n = n0 + nn;
                const bool fm = (kt == qb) && (n > wr);   // wave-uniform
                f32x4 acc = {0.f, 0.f, 0.f, 0.f};
                if (!fm) {
                    bf16x8 kh0 = *(const bf16x8*)&Khi[cur][(16 * n + lo) * KLD + hi * 8];
                    bf16x8 kh1 = *(const bf16x8*)&Khi[cur][(16 * n + lo) * KLD + 32 + hi * 8];
                    __builtin_amdgcn_s_setprio(1);
                    acc = __builtin_amdgcn_mfma_f32_16x16x32_bf16(qa0h, kh0, acc, 0, 0, 0);
                    acc = __builtin_amdgcn_mfma_f32_16x16x32_bf16(qa1h, kh1, acc, 0, 0, 0);
                    acc = __builtin_amdgcn_mfma_f32_16x16x32_bf16(qa0l, kh0, acc, 0, 0, 0);
                    acc = __builtin_amdgcn_mfma_f32_16x16x32_bf16(qa1l, kh1, acc, 0, 0, 0);
                    __builtin_amdgcn_s_setprio(0);
                }
                const int col = 16 * n + lo;
#pragma unroll
                for (int jx = 0; jx < 4; ++jx) {
                    const int row = wr * 16 + hi * 4 + jx;
                    const float p = (!fm && (kt < qb || col <= row)) ? __expf(acc[jx]) * il[jx] : 0.f;
                    Pf[pcur][row * PFLD + col] = p;
                }
            }
            BAR();
            vprev = (vprev == 2) ? 0 : vprev + 1;
            vstg  = (vstg  == 2) ? 0 : vstg  + 1;
        }
        // ---- epilogue: tile nkt-1 store + PV (after the loop's final BAR) ----
        {
            const int pl = (nkt - 1) & 1;
            const int vl = (nkt - 1) % 3;
            rowStore(pl, nkt - 1);
            pvStep(pl, vl);
        }
    }

    // ---- O (already normalized; own col half), fp32 ----
    {
        float* og = &Og[((size_t)(b * SEQ) + q0 + wr * 16 + hi * 4) * DIM + lo];
#pragma unroll
        for (int jx = 0; jx < 4; ++jx)
#pragma unroll
            for (int nn = 0; nn < 2; ++nn)
                og[jx * DIM + (n0 + nn) * 16] = o2[nn][jx];
    }
}

extern "C" void kernel_launch(void* const* d_in, const int* in_sizes, int n_in,
                              void* d_out, int out_size, void* d_ws, size_t ws_size,
                              hipStream_t stream) {
    const float* q = (const float*)d_in[0];
    const float* k = (const float*)d_in[1];
    const float* v = (const float*)d_in[2];
    float* out  = (float*)d_out;                        // [B,T,D] fp32
    float* smqk = out + (size_t)BATCHES * SEQ * DIM;    // [B,T,T] fp32

    sdpa_fused<<<NQB * BATCHES, 512, 0, stream>>>(q, k, v, out, smqk);
}